// Round 3
// baseline (190.793 us; speedup 1.0000x reference)
//
#include <hip/hip_runtime.h>
#include <stdint.h>

#define NSEQ 2048

typedef __attribute__((ext_vector_type(4))) float f32x4;
typedef __attribute__((ext_vector_type(8))) short s16x8;
typedef _Float16 f16x8 __attribute__((ext_vector_type(8)));

// workspace byte offsets
#define OFF_XT  0u            // [3][4][2048][256] f16 = 12 MB (dead after k_proj)
#define OFF_XA  0u            // [4][2048][256] f16 (combine out, k_final in)
#define OFF_PO  4194304u      // [2 split][16 bh][2048][64] f16 = 8 MB (inside old XT)
#define OFF_W   12582912u     // 4 * 65536 f16 = 512 KB
#define OFF_QR  13107200u     // [16][2048][64] f16, 4 MB
#define OFF_KR  17301504u     // [16][2048][64]
#define OFF_VT  21495808u     // [16][64][2048]
#define OFF_M   25690112u     // [2][16][2048] f32 running-max (log2 domain)
#define OFF_L   25952256u     // [2][16][2048] f32 running-sum

__device__ __forceinline__ short f2h(float f) {
  _Float16 h = (_Float16)f;
  return __builtin_bit_cast(short, h);
}
__device__ __forceinline__ float h2f(short s) {
  return (float)__builtin_bit_cast(_Float16, s);
}
// 64B-row tiles (GEMM staging, [128][32] f16)
__device__ __forceinline__ int swz64(int row, int slot) {
  return row * 64 + ((slot ^ ((row >> 1) & 3)) << 4);
}
// 128B-row tiles (attention, [*][64] f16): classic ^(row&7) on the 16B slot
__device__ __forceinline__ int swz128(int row, int slot) {
  return row * 128 + ((slot ^ (row & 7)) << 4);
}
#define MFMA(a, b, c) __builtin_amdgcn_mfma_f32_16x16x32_f16(a, b, c, 0, 0, 0)

// ---------------- kernel 1: weight cast (+ Wm reorder to k = h*64+d) ----------------
__global__ void k_convw(const float* __restrict__ Wq, const float* __restrict__ Wk,
                        const float* __restrict__ Wv, const float* __restrict__ Wm,
                        char* __restrict__ ws) {
  int o = blockIdx.x, which = blockIdx.y, i = threadIdx.x;
  const float* src = which == 0 ? Wq : which == 1 ? Wk : which == 2 ? Wv : Wm;
  short* dst = (short*)(ws + OFF_W) + which * 65536;
  float val = (which < 3) ? src[o * 256 + i] : src[o * 256 + ((i & 63) << 2) + (i >> 6)];
  dst[o * 256 + i] = f2h(val);
}

// ---------------- kernel 2: transpose-cast q/k/v [b][i][n] f32 -> [b][n][i] f16 ------
__global__ __launch_bounds__(256) void k_trans(const float* __restrict__ q,
    const float* __restrict__ k, const float* __restrict__ v, char* __restrict__ ws) {
  int tensor = blockIdx.z >> 2, b = blockIdx.z & 3;
  const float* src = tensor == 0 ? q : (tensor == 1 ? k : v);
  short* dst = (short*)(ws + OFF_XT) + (tensor * 4 + b) * 524288;
  int n0 = blockIdx.x * 64, i0 = blockIdx.y * 64;
  __shared__ float tile[64][65];
  int t = threadIdx.x;
  int nl = t & 63, ib = (t >> 6) * 16;
#pragma unroll
  for (int r = 0; r < 16; ++r)
    tile[ib + r][nl] = src[(b * 256 + i0 + ib + r) * 2048 + n0 + nl];
  __syncthreads();
  int nr = t >> 2, ic = (t & 3) * 16;
  short tmp[16];
#pragma unroll
  for (int j = 0; j < 16; ++j) tmp[j] = f2h(tile[ic + j][nr]);
  short* dp = &dst[(n0 + nr) * 256 + i0 + ic];
  *(s16x8*)dp = *(const s16x8*)&tmp[0];
  *(s16x8*)(dp + 8) = *(const s16x8*)&tmp[8];
}

// ---------------- shared 128x128 GEMM core (K=256), f16 MFMA -------------------------
__device__ __forceinline__ void gemm128(const short* __restrict__ W, const short* __restrict__ X,
                                        int o0, int n0, short* As, short* Bs, f32x4 acc[4][4]) {
  int t = threadIdx.x;
  int lane = t & 63, g = lane >> 4, c = lane & 15, wave = t >> 6;
  int wo = (wave >> 1) * 64, wn = (wave & 1) * 64;
  int row = t >> 2, slot = t & 3;
  for (int kk = 0; kk < 8; ++kk) {
    __syncthreads();
    int koff = kk * 32 + slot * 8;
    *(s16x8*)((char*)As + swz64(row, slot))      = *(const s16x8*)&W[(o0 + row) * 256 + koff];
    *(s16x8*)((char*)As + swz64(row + 64, slot)) = *(const s16x8*)&W[(o0 + row + 64) * 256 + koff];
    *(s16x8*)((char*)Bs + swz64(row, slot))      = *(const s16x8*)&X[(n0 + row) * 256 + koff];
    *(s16x8*)((char*)Bs + swz64(row + 64, slot)) = *(const s16x8*)&X[(n0 + row + 64) * 256 + koff];
    __syncthreads();
    f16x8 af[4], bfr[4];
#pragma unroll
    for (int f = 0; f < 4; ++f) {
      af[f]  = *(const f16x8*)((char*)As + swz64(wo + f * 16 + c, g));
      bfr[f] = *(const f16x8*)((char*)Bs + swz64(wn + f * 16 + c, g));
    }
#pragma unroll
    for (int i = 0; i < 4; ++i)
#pragma unroll
      for (int j = 0; j < 4; ++j)
        acc[i][j] = MFMA(af[i], bfr[j], acc[i][j]);
  }
}

// ---------------- kernel 3: QKV projection + bias + RoPE, coalesced epilogue ---------
__global__ __launch_bounds__(256) void k_proj(const float* __restrict__ enc,
    const float* __restrict__ bq, const float* __restrict__ bk, const float* __restrict__ bv,
    char* __restrict__ ws) {
  int proj = blockIdx.z >> 2, b = blockIdx.z & 3;
  const short* W = (const short*)(ws + OFF_W) + proj * 65536;
  const short* X = (const short*)(ws + OFF_XT) + (proj * 4 + b) * 524288;
  int o0 = blockIdx.y * 128, n0 = blockIdx.x * 128;
  __shared__ short As[128 * 32], Bs[128 * 32];
  __shared__ short Es[128 * 40];  // [n 128][d 32 + pad8]; 80B rows (16B-aligned)
  f32x4 acc[4][4] = {};
  gemm128(W, X, o0, n0, As, Bs, acc);
  int t = threadIdx.x, lane = t & 63, g = lane >> 4, c = lane & 15, wave = t >> 6;
  int wo = (wave >> 1) * 64, wn = (wave & 1) * 64;
  const float* bias = proj == 0 ? bq : (proj == 1 ? bk : bv);
  if (proj < 2) {
    // RoPE: C-layout rows o = ..+g*4+reg => h = reg, d = (o>>2) lane-constant;
    // pair (d, d±1) lives at lane^16 (g^1), same reg.
    // fold 1/sqrt(64) * log2(e) into Q so softmax runs in exp2 domain
    short* dst0 = (short*)(ws + (proj == 0 ? OFF_QR : OFF_KR));
    float scale = proj == 0 ? 0.18033688f : 1.0f;
    float sgn = (g & 1) ? 1.0f : -1.0f;
    int d0 = o0 >> 2;
    int srow = t >> 1, sseg = t & 1;
#pragma unroll
    for (int r = 0; r < 4; ++r) {   // head index
      __syncthreads();
#pragma unroll
      for (int i = 0; i < 4; ++i) {
        int ob = o0 + wo + i * 16 + g * 4;
        int d = ob >> 2;
        int dl = (wo >> 2) + i * 4 + g;
#pragma unroll
        for (int j = 0; j < 4; ++j) {
          int n = n0 + wn + j * 16 + c;
          float cv = enc[n * 64 + d], sv = enc[131072 + n * 64 + d];
          float val = acc[i][j][r] + bias[ob + r];
          float par = __shfl_xor(val, 16, 64);
          float res = (val * cv + sgn * par * sv) * scale;
          Es[(wn + j * 16 + c) * 40 + dl] = f2h(res);
        }
      }
      __syncthreads();
      // coalesced store: 128 rows x 64B (d-half of this o-block)
      short* dp = &dst0[((b * 4 + r) * 2048 + n0 + srow) * 64 + d0 + sseg * 16];
      const short* ep = &Es[srow * 40 + sseg * 16];
      *(s16x8*)dp = *(const s16x8*)ep;
      *(s16x8*)(dp + 8) = *(const s16x8*)(ep + 8);
    }
  } else {
    short* dst = (short*)(ws + OFF_VT);
#pragma unroll
    for (int i = 0; i < 4; ++i) {
      int ob = o0 + wo + i * 16 + g * 4;
      int d = ob >> 2;
#pragma unroll
      for (int j = 0; j < 4; ++j) {
        int n = n0 + wn + j * 16 + c;
#pragma unroll
        for (int r = 0; r < 4; ++r) {
          float val = acc[i][j][r] + bias[ob + r];
          dst[((b * 4 + r) * 64 + d) * 2048 + n] = f2h(val);  // [bh][d][m]
        }
      }
    }
  }
}

// ---------------- kernel 4: flash attention, split-KV x2, dbuf LDS, defer-max --------
__global__ __launch_bounds__(256, 4) void k_attn(char* __restrict__ ws) {
  int bh = blockIdx.y, ms = blockIdx.z;
  int t = threadIdx.x, wave = t >> 6, lane = t & 63, g = lane >> 4, c = lane & 15;
  int nw = blockIdx.x * 64 + wave * 16;  // this wave's 16 Q rows
  const short* Q = (const short*)(ws + OFF_QR) + bh * 131072;  // [2048][64]
  const short* K = (const short*)(ws + OFF_KR) + bh * 131072;
  const short* V = (const short*)(ws + OFF_VT) + bh * 131072;  // [64][2048]
  __shared__ short Ks[2][64 * 64], Vs[2][64 * 64], Ps[4][16 * 64];
  char* Pb = (char*)Ps[wave];
  f16x8 qf0 = *(const f16x8*)&Q[(nw + c) * 64 + g * 8];
  f16x8 qf1 = *(const f16x8*)&Q[(nw + c) * 64 + 32 + g * 8];
  f32x4 po[4] = {};
  float mrun[4], lrun[4];
#pragma unroll
  for (int r = 0; r < 4; ++r) { mrun[r] = -1e30f; lrun[r] = 0.f; }
  int sr = t >> 3, sl = t & 7;
  const int mb = ms * 1024;

  s16x8 RA[4], RB[4];
  auto LD = [&](int m0, s16x8* R) {
    R[0] = *(const s16x8*)&K[(m0 + sr) * 64 + sl * 8];
    R[1] = *(const s16x8*)&K[(m0 + sr + 32) * 64 + sl * 8];
    R[2] = *(const s16x8*)&V[sr * 2048 + m0 + sl * 8];
    R[3] = *(const s16x8*)&V[(sr + 32) * 2048 + m0 + sl * 8];
  };
  auto ST = [&](int buf, const s16x8* R) {
    *(s16x8*)((char*)Ks[buf] + swz128(sr, sl))      = R[0];
    *(s16x8*)((char*)Ks[buf] + swz128(sr + 32, sl)) = R[1];
    *(s16x8*)((char*)Vs[buf] + swz128(sr, sl))      = R[2];
    *(s16x8*)((char*)Vs[buf] + swz128(sr + 32, sl)) = R[3];
  };
  auto COMPUTE = [&](int buf) {
    const char* Kb = (const char*)Ks[buf];
    const char* Vb = (const char*)Vs[buf];
    // S = Q K^T (Q pre-scaled into exp2 domain)
    f32x4 s[4] = {};
    __builtin_amdgcn_s_setprio(1);
#pragma unroll
    for (int fj = 0; fj < 4; ++fj) {
      f16x8 k0 = *(const f16x8*)(Kb + swz128(fj * 16 + c, g));
      f16x8 k1 = *(const f16x8*)(Kb + swz128(fj * 16 + c, 4 + g));
      s[fj] = MFMA(qf0, k0, s[fj]);
      s[fj] = MFMA(qf1, k1, s[fj]);
    }
    __builtin_amdgcn_s_setprio(0);
    // online softmax (exp2 domain); rows live on 16-lane groups
    float pm[4], nm[4], rs[4];
#pragma unroll
    for (int r = 0; r < 4; ++r) {
      pm[r] = fmaxf(fmaxf(s[0][r], s[1][r]), fmaxf(s[2][r], s[3][r]));
#pragma unroll
      for (int d_ = 1; d_ < 16; d_ <<= 1) pm[r] = fmaxf(pm[r], __shfl_xor(pm[r], d_, 64));
    }
    bool grow = (pm[0] > mrun[0] + 11.5f) || (pm[1] > mrun[1] + 11.5f) ||
                (pm[2] > mrun[2] + 11.5f) || (pm[3] > mrun[3] + 11.5f);
    if (__any(grow)) {
#pragma unroll
      for (int r = 0; r < 4; ++r) {
        nm[r] = fmaxf(mrun[r], pm[r]);
        float corr = exp2f(mrun[r] - nm[r]);
        mrun[r] = nm[r];
        lrun[r] *= corr;
#pragma unroll
        for (int fd = 0; fd < 4; ++fd) po[fd][r] *= corr;
      }
    } else {
#pragma unroll
      for (int r = 0; r < 4; ++r) nm[r] = mrun[r];
    }
    float p[4][4];
#pragma unroll
    for (int r = 0; r < 4; ++r) rs[r] = 0.f;
#pragma unroll
    for (int fj = 0; fj < 4; ++fj)
#pragma unroll
      for (int r = 0; r < 4; ++r) {
        p[fj][r] = exp2f(s[fj][r] - nm[r]);
        rs[r] += p[fj][r];
      }
#pragma unroll
    for (int r = 0; r < 4; ++r) {
#pragma unroll
      for (int d_ = 1; d_ < 16; d_ <<= 1) rs[r] += __shfl_xor(rs[r], d_, 64);
      lrun[r] += rs[r];
    }
    // P -> per-wave LDS (f16), then PV
#pragma unroll
    for (int fj = 0; fj < 4; ++fj)
#pragma unroll
      for (int r = 0; r < 4; ++r) {
        int rr = g * 4 + r, mm = fj * 16 + c;
        *(short*)(Pb + swz128(rr, mm >> 3) + (mm & 7) * 2) = f2h(p[fj][r]);
      }
    asm volatile("s_waitcnt lgkmcnt(0)" ::: "memory");
    __builtin_amdgcn_sched_barrier(0);
    f16x8 pa0 = *(const f16x8*)(Pb + swz128(c, g));
    f16x8 pa1 = *(const f16x8*)(Pb + swz128(c, 4 + g));
    __builtin_amdgcn_s_setprio(1);
#pragma unroll
    for (int fd = 0; fd < 4; ++fd) {
      int dd = fd * 16 + c;
      f16x8 vb0 = *(const f16x8*)(Vb + swz128(dd, g));
      f16x8 vb1 = *(const f16x8*)(Vb + swz128(dd, 4 + g));
      po[fd] = MFMA(pa0, vb0, po[fd]);
      po[fd] = MFMA(pa1, vb1, po[fd]);
    }
    __builtin_amdgcn_s_setprio(0);
  };

  // software pipeline: 1 barrier per tile, prefetch 2 tiles deep
  LD(mb, RA); LD(mb + 64, RB);
  ST(0, RA);
  LD(mb + 128, RA);
  __syncthreads();
  for (int tt = 0; tt < 16; tt += 2) {
    ST(1, RB);
    if (tt + 3 < 16) LD(mb + (tt + 3) * 64, RB);
    COMPUTE(0);
    __syncthreads();
    if (tt + 2 < 16) {
      ST(0, RA);
      if (tt + 4 < 16) LD(mb + (tt + 4) * 64, RA);
    }
    COMPUTE(1);
    __syncthreads();
  }

  // write normalized partial O + (m, l) for combine
  short* PO = (short*)(ws + OFF_PO);
  float* Mm = (float*)(ws + OFF_M);
  float* Ll = (float*)(ws + OFF_L);
  int base = (ms * 16 + bh) * 2048;
#pragma unroll
  for (int fd = 0; fd < 4; ++fd) {
    int d = fd * 16 + c;
#pragma unroll
    for (int r = 0; r < 4; ++r) {
      int n = nw + g * 4 + r;
      PO[(base + n) * 64 + d] = f2h(po[fd][r] / lrun[r]);
    }
  }
  if (c == 0) {
#pragma unroll
    for (int r = 0; r < 4; ++r) {
      int n = nw + g * 4 + r;
      Mm[base + n] = mrun[r];
      Ll[base + n] = lrun[r];
    }
  }
}

// ---------------- kernel 4b: combine the two KV-split partials (exp2 domain) ---------
__global__ __launch_bounds__(256) void k_comb(char* __restrict__ ws) {
  int t = threadIdx.x;
  int row = blockIdx.x * 32 + (t >> 3);  // bh*2048 + n
  int bh = row >> 11, n = row & 2047;
  int dc = (t & 7) * 8;
  const short* PO = (const short*)(ws + OFF_PO);
  const float* Mm = (const float*)(ws + OFF_M);
  const float* Ll = (const float*)(ws + OFF_L);
  float m1 = Mm[row], m2 = Mm[32768 + row];
  float l1 = Ll[row], l2 = Ll[32768 + row];
  float M = fmaxf(m1, m2);
  float w1 = l1 * exp2f(m1 - M), w2 = l2 * exp2f(m2 - M);
  float inv = 1.f / (w1 + w2);
  float a1 = w1 * inv, a2 = w2 * inv;
  s16x8 o1 = *(const s16x8*)&PO[row * 64 + dc];
  s16x8 o2 = *(const s16x8*)&PO[(32768 + row) * 64 + dc];
  short res[8];
#pragma unroll
  for (int j = 0; j < 8; ++j) res[j] = f2h(a1 * h2f(o1[j]) + a2 * h2f(o2[j]));
  short* XA = (short*)(ws + OFF_XA);
  int b = bh >> 2, h = bh & 3;
  *(s16x8*)&XA[(b * 2048 + n) * 256 + h * 64 + dc] = *(const s16x8*)res;
}

// ---------------- kernel 5: output projection (fp32 out + bias) ----------------------
__global__ __launch_bounds__(256) void k_final(const float* __restrict__ bm,
    float* __restrict__ out, char* __restrict__ ws) {
  int b = blockIdx.z;
  const short* W = (const short*)(ws + OFF_W) + 3 * 65536;     // Wm reordered
  const short* X = (const short*)(ws + OFF_XA) + b * 524288;   // [2048][256]
  int o0 = blockIdx.y * 128, n0 = blockIdx.x * 128;
  __shared__ short As[128 * 32], Bs[128 * 32];
  f32x4 acc[4][4] = {};
  gemm128(W, X, o0, n0, As, Bs, acc);
  int t = threadIdx.x, lane = t & 63, g = lane >> 4, c = lane & 15, wave = t >> 6;
  int wo = (wave >> 1) * 64, wn = (wave & 1) * 64;
#pragma unroll
  for (int i = 0; i < 4; ++i) {
    int ob = o0 + wo + i * 16 + g * 4;
#pragma unroll
    for (int j = 0; j < 4; ++j) {
      int n = n0 + wn + j * 16 + c;
#pragma unroll
      for (int r = 0; r < 4; ++r)
        out[(b * 256 + ob + r) * 2048 + n] = acc[i][j][r] + bm[ob + r];
    }
  }
}

extern "C" void kernel_launch(void* const* d_in, const int* in_sizes, int n_in,
                              void* d_out, int out_size, void* d_ws, size_t ws_size,
                              hipStream_t stream) {
  (void)in_sizes; (void)n_in; (void)out_size; (void)ws_size;
  const float* q   = (const float*)d_in[0];
  const float* k   = (const float*)d_in[1];
  const float* v   = (const float*)d_in[2];
  const float* enc = (const float*)d_in[3];
  const float* Wq  = (const float*)d_in[4];
  const float* bq  = (const float*)d_in[5];
  const float* Wk  = (const float*)d_in[6];
  const float* bk  = (const float*)d_in[7];
  const float* Wv  = (const float*)d_in[8];
  const float* bv  = (const float*)d_in[9];
  const float* Wm  = (const float*)d_in[10];
  const float* bm  = (const float*)d_in[11];
  char* ws = (char*)d_ws;
  float* out = (float*)d_out;
  hipLaunchKernelGGL(k_convw, dim3(256, 4), dim3(256), 0, stream, Wq, Wk, Wv, Wm, ws);
  hipLaunchKernelGGL(k_trans, dim3(32, 4, 12), dim3(256), 0, stream, q, k, v, ws);
  hipLaunchKernelGGL(k_proj, dim3(16, 2, 12), dim3(256), 0, stream, enc, bq, bk, bv, ws);
  hipLaunchKernelGGL(k_attn, dim3(32, 16, 2), dim3(256), 0, stream, ws);
  hipLaunchKernelGGL(k_comb, dim3(1024), dim3(256), 0, stream, ws);
  hipLaunchKernelGGL(k_final, dim3(16, 2, 4), dim3(256), 0, stream, bm, out, ws);
}

// Round 4
// 161.478 us; speedup vs baseline: 1.1815x; 1.1815x over previous
//
#include <hip/hip_runtime.h>
#include <stdint.h>

#define NSEQ 2048

typedef __attribute__((ext_vector_type(4))) float f32x4;
typedef __attribute__((ext_vector_type(8))) short s16x8;
typedef _Float16 f16x8 __attribute__((ext_vector_type(8)));

// workspace byte offsets
#define OFF_XT  0u            // [3][4][2048][256] f16 = 12 MB (dead after k_proj)
#define OFF_XA  0u            // [4][2048][256] f16 (combine out, k_final in)
#define OFF_PO  4194304u      // [2 split][16 bh][2048][64] f16 = 8 MB (inside old XT)
#define OFF_W   12582912u     // 4 * 65536 f16 = 512 KB
#define OFF_QR  13107200u     // [16][2048][64] f16, 4 MB
#define OFF_KR  17301504u     // [16][2048][64]
#define OFF_VT  21495808u     // [16][64][2048]
#define OFF_M   25690112u     // [2][16][2048] f32 running-max (log2 domain)
#define OFF_L   25952256u     // [2][16][2048] f32 running-sum

__device__ __forceinline__ short f2h(float f) {
  _Float16 h = (_Float16)f;
  return __builtin_bit_cast(short, h);
}
__device__ __forceinline__ float h2f(short s) {
  return (float)__builtin_bit_cast(_Float16, s);
}
// 128B-row tiles ([*][64] f16): classic ^(row&7) on the 16B slot
__device__ __forceinline__ int swz128(int row, int slot) {
  return row * 128 + ((slot ^ (row & 7)) << 4);
}
#define MFMA(a, b, c) __builtin_amdgcn_mfma_f32_16x16x32_f16(a, b, c, 0, 0, 0)

// ---------------- kernel 1: weight cast (+ Wm reorder to k = h*64+d) ----------------
__global__ void k_convw(const float* __restrict__ Wq, const float* __restrict__ Wk,
                        const float* __restrict__ Wv, const float* __restrict__ Wm,
                        char* __restrict__ ws) {
  int o = blockIdx.x, which = blockIdx.y, i = threadIdx.x;
  const float* src = which == 0 ? Wq : which == 1 ? Wk : which == 2 ? Wv : Wm;
  short* dst = (short*)(ws + OFF_W) + which * 65536;
  float val = (which < 3) ? src[o * 256 + i] : src[o * 256 + ((i & 63) << 2) + (i >> 6)];
  dst[o * 256 + i] = f2h(val);
}

// ---------------- kernel 2: transpose-cast q/k/v [b][i][n] f32 -> [b][n][i] f16 ------
__global__ __launch_bounds__(256) void k_trans(const float* __restrict__ q,
    const float* __restrict__ k, const float* __restrict__ v, char* __restrict__ ws) {
  int tensor = blockIdx.z >> 2, b = blockIdx.z & 3;
  const float* src = tensor == 0 ? q : (tensor == 1 ? k : v);
  short* dst = (short*)(ws + OFF_XT) + (tensor * 4 + b) * 524288;
  int n0 = blockIdx.x * 64, i0 = blockIdx.y * 64;
  __shared__ float tile[64][65];
  int t = threadIdx.x;
  int nl = t & 63, ib = (t >> 6) * 16;
#pragma unroll
  for (int r = 0; r < 16; ++r)
    tile[ib + r][nl] = src[(b * 256 + i0 + ib + r) * 2048 + n0 + nl];
  __syncthreads();
  int nr = t >> 2, ic = (t & 3) * 16;
  short tmp[16];
#pragma unroll
  for (int j = 0; j < 16; ++j) tmp[j] = f2h(tile[ic + j][nr]);
  short* dp = &dst[(n0 + nr) * 256 + i0 + ic];
  *(s16x8*)dp = *(const s16x8*)&tmp[0];
  *(s16x8*)(dp + 8) = *(const s16x8*)&tmp[8];
}

// ------------- shared 128x128 GEMM core (K=256, BK=64 staging), f16 MFMA -------------
__device__ __forceinline__ void gemm128(const short* __restrict__ W, const short* __restrict__ X,
                                        int o0, int n0, short* As, short* Bs, f32x4 acc[4][4]) {
  int t = threadIdx.x;
  int lane = t & 63, g = lane >> 4, c = lane & 15, wave = t >> 6;
  int wo = (wave >> 1) * 64, wn = (wave & 1) * 64;
  int row = t >> 1, half = t & 1;
  for (int kk = 0; kk < 4; ++kk) {
    __syncthreads();
    int koff = kk * 64 + half * 32;
    const short* wsrc = &W[(o0 + row) * 256 + koff];
    const short* xsrc = &X[(n0 + row) * 256 + koff];
#pragma unroll
    for (int q4 = 0; q4 < 4; ++q4) {
      *(s16x8*)((char*)As + swz128(row, half * 4 + q4)) = *(const s16x8*)(wsrc + q4 * 8);
      *(s16x8*)((char*)Bs + swz128(row, half * 4 + q4)) = *(const s16x8*)(xsrc + q4 * 8);
    }
    __syncthreads();
#pragma unroll
    for (int ks = 0; ks < 2; ++ks) {
      f16x8 af[4], bfr[4];
#pragma unroll
      for (int f = 0; f < 4; ++f) {
        af[f]  = *(const f16x8*)((char*)As + swz128(wo + f * 16 + c, ks * 4 + g));
        bfr[f] = *(const f16x8*)((char*)Bs + swz128(wn + f * 16 + c, ks * 4 + g));
      }
#pragma unroll
      for (int i = 0; i < 4; ++i)
#pragma unroll
        for (int j = 0; j < 4; ++j)
          acc[i][j] = MFMA(af[i], bfr[j], acc[i][j]);
    }
  }
}

// ---------------- kernel 3: QKV projection + bias + RoPE ----------------------------
__global__ __launch_bounds__(256) void k_proj(const float* __restrict__ enc,
    const float* __restrict__ bq, const float* __restrict__ bk, const float* __restrict__ bv,
    char* __restrict__ ws) {
  int proj = blockIdx.z >> 2, b = blockIdx.z & 3;
  const short* W = (const short*)(ws + OFF_W) + proj * 65536;
  const short* X = (const short*)(ws + OFF_XT) + (proj * 4 + b) * 524288;
  int o0 = blockIdx.y * 128, n0 = blockIdx.x * 128;
  __shared__ short As[128 * 64], Bs[128 * 64];
  f32x4 acc[4][4] = {};
  gemm128(W, X, o0, n0, As, Bs, acc);
  int t = threadIdx.x, lane = t & 63, g = lane >> 4, c = lane & 15, wave = t >> 6;
  int wo = (wave >> 1) * 64, wn = (wave & 1) * 64;
  const float* bias = proj == 0 ? bq : (proj == 1 ? bk : bv);
  if (proj < 2) {
    // RoPE: C-layout rows o = ..+g*4+reg => h = reg, d = (o>>2) lane-constant;
    // pair (d, d±1) lives at lane^16 (g^1), same reg.
    // fold 1/sqrt(64) * log2(e) into Q so softmax runs in exp2 domain
    short* dst0 = (short*)(ws + (proj == 0 ? OFF_QR : OFF_KR));
    float scale = proj == 0 ? 0.18033688f : 1.0f;
    float sgn = (g & 1) ? 1.0f : -1.0f;
#pragma unroll
    for (int i = 0; i < 4; ++i) {
      int ob = o0 + wo + i * 16 + g * 4;
      int d = ob >> 2;
#pragma unroll
      for (int j = 0; j < 4; ++j) {
        int n = n0 + wn + j * 16 + c;
        float cv = enc[n * 64 + d], sv = enc[131072 + n * 64 + d];
#pragma unroll
        for (int r = 0; r < 4; ++r) {
          float val = acc[i][j][r] + bias[ob + r];
          float par = __shfl_xor(val, 16, 64);
          float res = (val * cv + sgn * par * sv) * scale;
          dst0[((b * 4 + r) * 2048 + n) * 64 + d] = f2h(res);  // [bh][n][d]
        }
      }
    }
  } else {
    short* dst = (short*)(ws + OFF_VT);
#pragma unroll
    for (int i = 0; i < 4; ++i) {
      int ob = o0 + wo + i * 16 + g * 4;
      int d = ob >> 2;
#pragma unroll
      for (int j = 0; j < 4; ++j) {
        int n = n0 + wn + j * 16 + c;
#pragma unroll
        for (int r = 0; r < 4; ++r) {
          float val = acc[i][j][r] + bias[ob + r];
          dst[((b * 4 + r) * 64 + d) * 2048 + n] = f2h(val);  // [bh][d][m]
        }
      }
    }
  }
}

// ------- kernel 4: flash attention, split-KV x2, swapped QK^T (lane-local rows) ------
__global__ __launch_bounds__(256, 4) void k_attn(char* __restrict__ ws) {
  int bh = blockIdx.y, ms = blockIdx.z;
  int t = threadIdx.x, wave = t >> 6, lane = t & 63, g = lane >> 4, c = lane & 15;
  int nw = blockIdx.x * 64 + wave * 16;  // this wave's 16 Q rows
  const short* Q = (const short*)(ws + OFF_QR) + bh * 131072;  // [2048][64]
  const short* K = (const short*)(ws + OFF_KR) + bh * 131072;
  const short* V = (const short*)(ws + OFF_VT) + bh * 131072;  // [64][2048]
  __shared__ short Ks[64 * 64], Vs[64 * 64], Ps[4][16 * 64];
  char* Pb = (char*)Ps[wave];
  f16x8 qf0 = *(const f16x8*)&Q[(nw + c) * 64 + g * 8];
  f16x8 qf1 = *(const f16x8*)&Q[(nw + c) * 64 + 32 + g * 8];
  f32x4 po[4] = {};
  float mrun = -1e30f, lrun = 0.f;   // per-lane scalars: softmax state of q-row (nw+c)
  int sr = t >> 3, sl = t & 7;
  const int mb = ms * 1024;
  int bsrc = g * 16 + g * 4;         // bpermute base: lane in same g-group holding row g*4+r

  s16x8 RA[4], RB[4];
  auto LD = [&](int m0, s16x8* R) {
    R[0] = *(const s16x8*)&K[(m0 + sr) * 64 + sl * 8];
    R[1] = *(const s16x8*)&K[(m0 + sr + 32) * 64 + sl * 8];
    R[2] = *(const s16x8*)&V[sr * 2048 + m0 + sl * 8];
    R[3] = *(const s16x8*)&V[(sr + 32) * 2048 + m0 + sl * 8];
  };
  auto ST = [&](const s16x8* R) {
    *(s16x8*)((char*)Ks + swz128(sr, sl))      = R[0];
    *(s16x8*)((char*)Ks + swz128(sr + 32, sl)) = R[1];
    *(s16x8*)((char*)Vs + swz128(sr, sl))      = R[2];
    *(s16x8*)((char*)Vs + swz128(sr + 32, sl)) = R[3];
  };
  auto COMPUTE = [&]() {
    // S^T = K Q^T : row = m = fj*16 + g*4 + r, col = n = c (lane-local q-row!)
    f32x4 s[4] = {};
    __builtin_amdgcn_s_setprio(1);
#pragma unroll
    for (int fj = 0; fj < 4; ++fj) {
      f16x8 k0 = *(const f16x8*)((char*)Ks + swz128(fj * 16 + c, g));
      f16x8 k1 = *(const f16x8*)((char*)Ks + swz128(fj * 16 + c, 4 + g));
      s[fj] = MFMA(k0, qf0, s[fj]);
      s[fj] = MFMA(k1, qf1, s[fj]);
    }
    __builtin_amdgcn_s_setprio(0);
    // row-max: in-register tree over 16, then 2 cross-lane rounds (xor16, xor32)
    float t0 = fmaxf(fmaxf(s[0][0], s[0][1]), fmaxf(s[0][2], s[0][3]));
    float t1 = fmaxf(fmaxf(s[1][0], s[1][1]), fmaxf(s[1][2], s[1][3]));
    float t2 = fmaxf(fmaxf(s[2][0], s[2][1]), fmaxf(s[2][2], s[2][3]));
    float t3 = fmaxf(fmaxf(s[3][0], s[3][1]), fmaxf(s[3][2], s[3][3]));
    float rmax = fmaxf(fmaxf(t0, t1), fmaxf(t2, t3));
    rmax = fmaxf(rmax, __shfl_xor(rmax, 16, 64));
    rmax = fmaxf(rmax, __shfl_xor(rmax, 32, 64));
    // defer-max: only rescale when the running max grows materially (exp2 domain)
    if (__any(rmax > mrun + 11.5f)) {
      float nm = fmaxf(mrun, rmax);
      float corr = exp2f(mrun - nm);
      mrun = nm;
      lrun *= corr;
#pragma unroll
      for (int r = 0; r < 4; ++r) {
        float corr_r = __shfl(corr, bsrc + r, 64);  // corr of row g*4+r
#pragma unroll
        for (int fd = 0; fd < 4; ++fd) po[fd][r] *= corr_r;
      }
    }
    float p[4][4], rs = 0.f;
#pragma unroll
    for (int fj = 0; fj < 4; ++fj) {
      f32x4 pv;
#pragma unroll
      for (int r = 0; r < 4; ++r) {
        pv[r] = exp2f(s[fj][r] - mrun);
        p[fj][r] = pv[r];
      }
      rs += (pv[0] + pv[1]) + (pv[2] + pv[3]);
    }
    rs += __shfl_xor(rs, 16, 64);
    rs += __shfl_xor(rs, 32, 64);
    lrun += rs;
    // P^T -> Ps as P[n=c][m] rows (A-frag layout for PV)
#pragma unroll
    for (int fj = 0; fj < 4; ++fj)
#pragma unroll
      for (int r = 0; r < 4; ++r) {
        int mm = fj * 16 + g * 4 + r;
        *(short*)(Pb + swz128(c, mm >> 3) + (mm & 7) * 2) = f2h(p[fj][r]);
      }
    asm volatile("s_waitcnt lgkmcnt(0)" ::: "memory");
    __builtin_amdgcn_sched_barrier(0);
    f16x8 pa0 = *(const f16x8*)(Pb + swz128(c, g));
    f16x8 pa1 = *(const f16x8*)(Pb + swz128(c, 4 + g));
    __builtin_amdgcn_s_setprio(1);
#pragma unroll
    for (int fd = 0; fd < 4; ++fd) {
      int dd = fd * 16 + c;
      f16x8 vb0 = *(const f16x8*)((char*)Vs + swz128(dd, g));
      f16x8 vb1 = *(const f16x8*)((char*)Vs + swz128(dd, 4 + g));
      po[fd] = MFMA(pa0, vb0, po[fd]);
      po[fd] = MFMA(pa1, vb1, po[fd]);
    }
    __builtin_amdgcn_s_setprio(0);
  };

  LD(mb, RA);
  for (int tt = 0; tt < 16; tt += 2) {
    __syncthreads();                 // prior tile's LDS reads complete
    ST(RA);
    LD(mb + (tt + 1) * 64, RB);      // prefetch hides under compute
    __syncthreads();
    COMPUTE();
    __syncthreads();
    ST(RB);
    if (tt + 2 < 16) LD(mb + (tt + 2) * 64, RA);
    __syncthreads();
    COMPUTE();
  }

  // write normalized partial O + (m, l) for combine
  short* PO = (short*)(ws + OFF_PO);
  float* Mm = (float*)(ws + OFF_M);
  float* Ll = (float*)(ws + OFF_L);
  int base = (ms * 16 + bh) * 2048;
  float li[4];
#pragma unroll
  for (int r = 0; r < 4; ++r) li[r] = 1.0f / __shfl(lrun, bsrc + r, 64);
#pragma unroll
  for (int fd = 0; fd < 4; ++fd) {
    int d = fd * 16 + c;
#pragma unroll
    for (int r = 0; r < 4; ++r) {
      int n = nw + g * 4 + r;
      PO[(base + n) * 64 + d] = f2h(po[fd][r] * li[r]);
    }
  }
  if (g == 0) {
    Mm[base + nw + c] = mrun;
    Ll[base + nw + c] = lrun;
  }
}

// ---------------- kernel 4b: combine the two KV-split partials (exp2 domain) ---------
__global__ __launch_bounds__(256) void k_comb(char* __restrict__ ws) {
  int t = threadIdx.x;
  int row = blockIdx.x * 32 + (t >> 3);  // bh*2048 + n
  int bh = row >> 11, n = row & 2047;
  int dc = (t & 7) * 8;
  const short* PO = (const short*)(ws + OFF_PO);
  const float* Mm = (const float*)(ws + OFF_M);
  const float* Ll = (const float*)(ws + OFF_L);
  float m1 = Mm[row], m2 = Mm[32768 + row];
  float l1 = Ll[row], l2 = Ll[32768 + row];
  float M = fmaxf(m1, m2);
  float w1 = l1 * exp2f(m1 - M), w2 = l2 * exp2f(m2 - M);
  float inv = 1.f / (w1 + w2);
  float a1 = w1 * inv, a2 = w2 * inv;
  s16x8 o1 = *(const s16x8*)&PO[row * 64 + dc];
  s16x8 o2 = *(const s16x8*)&PO[(32768 + row) * 64 + dc];
  short res[8];
#pragma unroll
  for (int j = 0; j < 8; ++j) res[j] = f2h(a1 * h2f(o1[j]) + a2 * h2f(o2[j]));
  short* XA = (short*)(ws + OFF_XA);
  int b = bh >> 2, h = bh & 3;
  *(s16x8*)&XA[(b * 2048 + n) * 256 + h * 64 + dc] = *(const s16x8*)res;
}

// ---------------- kernel 5: output projection (fp32 out + bias) ----------------------
__global__ __launch_bounds__(256) void k_final(const float* __restrict__ bm,
    float* __restrict__ out, char* __restrict__ ws) {
  int b = blockIdx.z;
  const short* W = (const short*)(ws + OFF_W) + 3 * 65536;     // Wm reordered
  const short* X = (const short*)(ws + OFF_XA) + b * 524288;   // [2048][256]
  int o0 = blockIdx.y * 128, n0 = blockIdx.x * 128;
  __shared__ short As[128 * 64], Bs[128 * 64];
  f32x4 acc[4][4] = {};
  gemm128(W, X, o0, n0, As, Bs, acc);
  int t = threadIdx.x, lane = t & 63, g = lane >> 4, c = lane & 15, wave = t >> 6;
  int wo = (wave >> 1) * 64, wn = (wave & 1) * 64;
#pragma unroll
  for (int i = 0; i < 4; ++i) {
    int ob = o0 + wo + i * 16 + g * 4;
#pragma unroll
    for (int j = 0; j < 4; ++j) {
      int n = n0 + wn + j * 16 + c;
#pragma unroll
      for (int r = 0; r < 4; ++r)
        out[(b * 256 + ob + r) * 2048 + n] = acc[i][j][r] + bm[ob + r];
    }
  }
}

extern "C" void kernel_launch(void* const* d_in, const int* in_sizes, int n_in,
                              void* d_out, int out_size, void* d_ws, size_t ws_size,
                              hipStream_t stream) {
  (void)in_sizes; (void)n_in; (void)out_size; (void)ws_size;
  const float* q   = (const float*)d_in[0];
  const float* k   = (const float*)d_in[1];
  const float* v   = (const float*)d_in[2];
  const float* enc = (const float*)d_in[3];
  const float* Wq  = (const float*)d_in[4];
  const float* bq  = (const float*)d_in[5];
  const float* Wk  = (const float*)d_in[6];
  const float* bk  = (const float*)d_in[7];
  const float* Wv  = (const float*)d_in[8];
  const float* bv  = (const float*)d_in[9];
  const float* Wm  = (const float*)d_in[10];
  const float* bm  = (const float*)d_in[11];
  char* ws = (char*)d_ws;
  float* out = (float*)d_out;
  hipLaunchKernelGGL(k_convw, dim3(256, 4), dim3(256), 0, stream, Wq, Wk, Wv, Wm, ws);
  hipLaunchKernelGGL(k_trans, dim3(32, 4, 12), dim3(256), 0, stream, q, k, v, ws);
  hipLaunchKernelGGL(k_proj, dim3(16, 2, 12), dim3(256), 0, stream, enc, bq, bk, bv, ws);
  hipLaunchKernelGGL(k_attn, dim3(32, 16, 2), dim3(256), 0, stream, ws);
  hipLaunchKernelGGL(k_comb, dim3(1024), dim3(256), 0, stream, ws);
  hipLaunchKernelGGL(k_final, dim3(16, 2, 4), dim3(256), 0, stream, bm, out, ws);
}

// Round 7
// 161.119 us; speedup vs baseline: 1.1842x; 1.0022x over previous
//
#include <hip/hip_runtime.h>
#include <stdint.h>

#define NSEQ 2048

typedef __attribute__((ext_vector_type(4))) float f32x4;
typedef __attribute__((ext_vector_type(8))) short s16x8;
typedef _Float16 f16x8 __attribute__((ext_vector_type(8)));

// workspace byte offsets
#define OFF_XT  0u            // [3][4][2048][256] f16 = 12 MB (dead after k_proj)
#define OFF_PO  0u            // [4 split][16 bh][2048][64] f16 = 16 MB (aliases dead XT)
#define OFF_M   16777216u     // [4][16][2048] f32 running-max (log2 domain), 512 KB
#define OFF_L   17301504u     // [4][16][2048] f32 running-sum, 512 KB
#define OFF_QR  17825792u     // [16][2048][64] f16, 4 MB
#define OFF_KR  22020096u     // [16][2048][64]
#define OFF_VT  26214400u     // [16][64][2048]   (ws end ~29 MB)

__device__ __forceinline__ short f2h(float f) {
  _Float16 h = (_Float16)f;
  return __builtin_bit_cast(short, h);
}
__device__ __forceinline__ float h2f(short s) {
  return (float)__builtin_bit_cast(_Float16, s);
}
// 128B-row tiles ([*][64] f16): classic ^(row&7) on the 16B slot
__device__ __forceinline__ int swz128(int row, int slot) {
  return row * 128 + ((slot ^ (row & 7)) << 4);
}
#define MFMA(a, b, c) __builtin_amdgcn_mfma_f32_16x16x32_f16(a, b, c, 0, 0, 0)

// ---------------- kernel 1: transpose-cast q/k/v [b][i][n] f32 -> [b][n][i] f16 ------
__global__ __launch_bounds__(256) void k_trans(const float* __restrict__ q,
    const float* __restrict__ k, const float* __restrict__ v, char* __restrict__ ws) {
  int tensor = blockIdx.z >> 2, b = blockIdx.z & 3;
  const float* src = tensor == 0 ? q : (tensor == 1 ? k : v);
  short* dst = (short*)(ws + OFF_XT) + (tensor * 4 + b) * 524288;
  int n0 = blockIdx.x * 64, i0 = blockIdx.y * 64;
  __shared__ float tile[64][65];
  int t = threadIdx.x;
  int nl = t & 63, ib = (t >> 6) * 16;
#pragma unroll
  for (int r = 0; r < 16; ++r)
    tile[ib + r][nl] = src[(b * 256 + i0 + ib + r) * 2048 + n0 + nl];
  __syncthreads();
  int nr = t >> 2, ic = (t & 3) * 16;
  short tmp[16];
#pragma unroll
  for (int j = 0; j < 16; ++j) tmp[j] = f2h(tile[ic + j][nr]);
  short* dp = &dst[(n0 + nr) * 256 + i0 + ic];
  *(s16x8*)dp = *(const s16x8*)&tmp[0];
  *(s16x8*)(dp + 8) = *(const s16x8*)&tmp[8];
}

// ------- kernel 2: QKV projection (64x64 tile, W cast fused) + bias + RoPE ----------
__global__ __launch_bounds__(256) void k_proj(const float* __restrict__ Wq,
    const float* __restrict__ Wk, const float* __restrict__ Wv,
    const float* __restrict__ enc, const float* __restrict__ bq,
    const float* __restrict__ bk, const float* __restrict__ bv, char* __restrict__ ws) {
  int proj = blockIdx.z >> 2, b = blockIdx.z & 3;
  const float* W = proj == 0 ? Wq : (proj == 1 ? Wk : Wv);
  const short* X = (const short*)(ws + OFF_XT) + (proj * 4 + b) * 524288;
  int o0 = blockIdx.y * 64, n0 = blockIdx.x * 64;
  __shared__ short As[64 * 64], Bs[64 * 64];
  int t = threadIdx.x, lane = t & 63, g = lane >> 4, c = lane & 15, wave = t >> 6;
  int wr = wave >> 1, wc = wave & 1;
  int row = t >> 2, seg = t & 3;
  f32x4 acc[2][2] = {};
  for (int kk = 0; kk < 4; ++kk) {
    __syncthreads();
    int koff = kk * 64;
    // A: W f32 -> f16 in-staging (16 f16 per thread)
    const float* wsrc = &W[(o0 + row) * 256 + koff + seg * 16];
    short ha[16];
#pragma unroll
    for (int q4 = 0; q4 < 4; ++q4) {
      f32x4 wv4 = *(const f32x4*)(wsrc + q4 * 4);
#pragma unroll
      for (int j = 0; j < 4; ++j) ha[q4 * 4 + j] = f2h(wv4[j]);
    }
    *(s16x8*)((char*)As + swz128(row, seg * 2))     = *(const s16x8*)&ha[0];
    *(s16x8*)((char*)As + swz128(row, seg * 2 + 1)) = *(const s16x8*)&ha[8];
    // B from XT (f16)
    const short* xsrc = &X[(n0 + row) * 256 + koff];
    *(s16x8*)((char*)Bs + swz128(row, seg))     = *(const s16x8*)(xsrc + seg * 8);
    *(s16x8*)((char*)Bs + swz128(row, 4 + seg)) = *(const s16x8*)(xsrc + 32 + seg * 8);
    __syncthreads();
#pragma unroll
    for (int ks = 0; ks < 2; ++ks) {
      f16x8 af[2], bfr[2];
#pragma unroll
      for (int f = 0; f < 2; ++f) {
        af[f]  = *(const f16x8*)((char*)As + swz128(wr * 32 + f * 16 + c, ks * 4 + g));
        bfr[f] = *(const f16x8*)((char*)Bs + swz128(wc * 32 + f * 16 + c, ks * 4 + g));
      }
#pragma unroll
      for (int i = 0; i < 2; ++i)
#pragma unroll
        for (int j = 0; j < 2; ++j)
          acc[i][j] = MFMA(af[i], bfr[j], acc[i][j]);
    }
  }
  const float* bias = proj == 0 ? bq : (proj == 1 ? bk : bv);
  if (proj < 2) {
    // RoPE: h = reg r, d = (o>>2); pair (d, d±1) at lane^16, same reg.
    // fold 1/sqrt(64) * log2(e) into Q so softmax runs in exp2 domain
    short* dst0 = (short*)(ws + (proj == 0 ? OFF_QR : OFF_KR));
    float scale = proj == 0 ? 0.18033688f : 1.0f;
    float sgn = (g & 1) ? 1.0f : -1.0f;
#pragma unroll
    for (int i = 0; i < 2; ++i) {
      int ob = o0 + wr * 32 + i * 16 + g * 4;
      int d = ob >> 2;
#pragma unroll
      for (int j = 0; j < 2; ++j) {
        int n = n0 + wc * 32 + j * 16 + c;
        float cv = enc[n * 64 + d], sv = enc[131072 + n * 64 + d];
#pragma unroll
        for (int r = 0; r < 4; ++r) {
          float val = acc[i][j][r] + bias[ob + r];
          float par = __shfl_xor(val, 16, 64);
          float res = (val * cv + sgn * par * sv) * scale;
          dst0[((b * 4 + r) * 2048 + n) * 64 + d] = f2h(res);  // [bh][n][d]
        }
      }
    }
  } else {
    short* dst = (short*)(ws + OFF_VT);
#pragma unroll
    for (int i = 0; i < 2; ++i) {
      int ob = o0 + wr * 32 + i * 16 + g * 4;
      int d = ob >> 2;
#pragma unroll
      for (int j = 0; j < 2; ++j) {
        int n = n0 + wc * 32 + j * 16 + c;
#pragma unroll
        for (int r = 0; r < 4; ++r) {
          float val = acc[i][j][r] + bias[ob + r];
          dst[((b * 4 + r) * 64 + d) * 2048 + n] = f2h(val);  // [bh][d][m]
        }
      }
    }
  }
}

// ------- kernel 3: flash attention, split-KV x4, swapped QK^T (lane-local rows) ------
__global__ __launch_bounds__(256, 4) void k_attn(char* __restrict__ ws) {
  int bh = blockIdx.y, ms = blockIdx.z;
  int t = threadIdx.x, wave = t >> 6, lane = t & 63, g = lane >> 4, c = lane & 15;
  int nw = blockIdx.x * 64 + wave * 16;  // this wave's 16 Q rows
  const short* Q = (const short*)(ws + OFF_QR) + bh * 131072;  // [2048][64]
  const short* K = (const short*)(ws + OFF_KR) + bh * 131072;
  const short* V = (const short*)(ws + OFF_VT) + bh * 131072;  // [64][2048]
  __shared__ short Ks[64 * 64], Vs[64 * 64], Ps[4][16 * 64];
  char* Pb = (char*)Ps[wave];
  f16x8 qf0 = *(const f16x8*)&Q[(nw + c) * 64 + g * 8];
  f16x8 qf1 = *(const f16x8*)&Q[(nw + c) * 64 + 32 + g * 8];
  f32x4 po[4] = {};
  float mrun = -1e30f, lrun = 0.f;   // per-lane scalars: softmax state of q-row (nw+c)
  int sr = t >> 3, sl = t & 7;
  const int mb = ms * 512;
  int bsrc = g * 16 + g * 4;         // shfl base: lane in same g-group holding row g*4+r

  s16x8 RA[4], RB[4];
  auto LD = [&](int m0, s16x8* R) {
    R[0] = *(const s16x8*)&K[(m0 + sr) * 64 + sl * 8];
    R[1] = *(const s16x8*)&K[(m0 + sr + 32) * 64 + sl * 8];
    R[2] = *(const s16x8*)&V[sr * 2048 + m0 + sl * 8];
    R[3] = *(const s16x8*)&V[(sr + 32) * 2048 + m0 + sl * 8];
  };
  auto ST = [&](const s16x8* R) {
    *(s16x8*)((char*)Ks + swz128(sr, sl))      = R[0];
    *(s16x8*)((char*)Ks + swz128(sr + 32, sl)) = R[1];
    *(s16x8*)((char*)Vs + swz128(sr, sl))      = R[2];
    *(s16x8*)((char*)Vs + swz128(sr + 32, sl)) = R[3];
  };
  auto COMPUTE = [&]() {
    // S^T = K Q^T : row = m = fj*16 + g*4 + r, col = n = c (lane-local q-row!)
    f32x4 s[4] = {};
    __builtin_amdgcn_s_setprio(1);
#pragma unroll
    for (int fj = 0; fj < 4; ++fj) {
      f16x8 k0 = *(const f16x8*)((char*)Ks + swz128(fj * 16 + c, g));
      f16x8 k1 = *(const f16x8*)((char*)Ks + swz128(fj * 16 + c, 4 + g));
      s[fj] = MFMA(k0, qf0, s[fj]);
      s[fj] = MFMA(k1, qf1, s[fj]);
    }
    __builtin_amdgcn_s_setprio(0);
    // row-max: in-register tree over 16, then 2 cross-lane rounds (xor16, xor32)
    float t0 = fmaxf(fmaxf(s[0][0], s[0][1]), fmaxf(s[0][2], s[0][3]));
    float t1 = fmaxf(fmaxf(s[1][0], s[1][1]), fmaxf(s[1][2], s[1][3]));
    float t2 = fmaxf(fmaxf(s[2][0], s[2][1]), fmaxf(s[2][2], s[2][3]));
    float t3 = fmaxf(fmaxf(s[3][0], s[3][1]), fmaxf(s[3][2], s[3][3]));
    float rmax = fmaxf(fmaxf(t0, t1), fmaxf(t2, t3));
    rmax = fmaxf(rmax, __shfl_xor(rmax, 16, 64));
    rmax = fmaxf(rmax, __shfl_xor(rmax, 32, 64));
    // defer-max: only rescale when the running max grows materially (exp2 domain)
    if (__any(rmax > mrun + 11.5f)) {
      float nm = fmaxf(mrun, rmax);
      float corr = exp2f(mrun - nm);
      mrun = nm;
      lrun *= corr;
#pragma unroll
      for (int r = 0; r < 4; ++r) {
        float corr_r = __shfl(corr, bsrc + r, 64);  // corr of row g*4+r
#pragma unroll
        for (int fd = 0; fd < 4; ++fd) po[fd][r] *= corr_r;
      }
    }
    float p[4][4], rs = 0.f;
#pragma unroll
    for (int fj = 0; fj < 4; ++fj) {
      f32x4 pv;
#pragma unroll
      for (int r = 0; r < 4; ++r) {
        pv[r] = exp2f(s[fj][r] - mrun);
        p[fj][r] = pv[r];
      }
      rs += (pv[0] + pv[1]) + (pv[2] + pv[3]);
    }
    rs += __shfl_xor(rs, 16, 64);
    rs += __shfl_xor(rs, 32, 64);
    lrun += rs;
    // P^T -> Ps as P[n=c][m] rows (A-frag layout for PV)
#pragma unroll
    for (int fj = 0; fj < 4; ++fj)
#pragma unroll
      for (int r = 0; r < 4; ++r) {
        int mm = fj * 16 + g * 4 + r;
        *(short*)(Pb + swz128(c, mm >> 3) + (mm & 7) * 2) = f2h(p[fj][r]);
      }
    asm volatile("s_waitcnt lgkmcnt(0)" ::: "memory");
    __builtin_amdgcn_sched_barrier(0);
    f16x8 pa0 = *(const f16x8*)(Pb + swz128(c, g));
    f16x8 pa1 = *(const f16x8*)(Pb + swz128(c, 4 + g));
    __builtin_amdgcn_s_setprio(1);
#pragma unroll
    for (int fd = 0; fd < 4; ++fd) {
      int dd = fd * 16 + c;
      f16x8 vb0 = *(const f16x8*)((char*)Vs + swz128(dd, g));
      f16x8 vb1 = *(const f16x8*)((char*)Vs + swz128(dd, 4 + g));
      po[fd] = MFMA(pa0, vb0, po[fd]);
      po[fd] = MFMA(pa1, vb1, po[fd]);
    }
    __builtin_amdgcn_s_setprio(0);
  };

  LD(mb, RA);
  for (int tt = 0; tt < 8; tt += 2) {
    __syncthreads();                 // prior tile's LDS reads complete
    ST(RA);
    LD(mb + (tt + 1) * 64, RB);      // prefetch hides under compute
    __syncthreads();
    COMPUTE();
    __syncthreads();
    ST(RB);
    if (tt + 2 < 8) LD(mb + (tt + 2) * 64, RA);
    __syncthreads();
    COMPUTE();
  }

  // write normalized partial O + (m, l) for combine
  short* PO = (short*)(ws + OFF_PO);
  float* Mm = (float*)(ws + OFF_M);
  float* Ll = (float*)(ws + OFF_L);
  int base = (ms * 16 + bh) * 2048;
  float li[4];
#pragma unroll
  for (int r = 0; r < 4; ++r) li[r] = 1.0f / __shfl(lrun, bsrc + r, 64);
#pragma unroll
  for (int fd = 0; fd < 4; ++fd) {
    int d = fd * 16 + c;
#pragma unroll
    for (int r = 0; r < 4; ++r) {
      int n = nw + g * 4 + r;
      PO[(base + n) * 64 + d] = f2h(po[fd][r] * li[r]);
    }
  }
  if (g == 0) {
    Mm[base + nw + c] = mrun;
    Ll[base + nw + c] = lrun;
  }
}

// ------- kernel 4: output projection (64x64), split-combine fused in B-staging ------
__global__ __launch_bounds__(256) void k_final(const float* __restrict__ Wm,
    const float* __restrict__ bm, float* __restrict__ out, char* __restrict__ ws) {
  int b = blockIdx.z;
  int o0 = blockIdx.y * 64, n0 = blockIdx.x * 64;
  const short* PO = (const short*)(ws + OFF_PO);
  const float* Mm = (const float*)(ws + OFF_M);
  const float* Ll = (const float*)(ws + OFF_L);
  __shared__ short As[64 * 64], Bs[64 * 64];
  int t = threadIdx.x, lane = t & 63, g = lane >> 4, c = lane & 15, wave = t >> 6;
  int wr = wave >> 1, wc = wave & 1;
  int row = t >> 2, seg = t & 3;
  f32x4 acc[2][2] = {};
  for (int kk = 0; kk < 4; ++kk) {   // kk = head h; local k = d within head
    __syncthreads();
    // A: Wm gather-reorder (Wm_r[o][h*64+d] = Wm[o][d*4+h]) + f32->f16
    short ha[16];
#pragma unroll
    for (int j = 0; j < 16; ++j)
      ha[j] = f2h(Wm[(o0 + row) * 256 + (seg * 16 + j) * 4 + kk]);
    *(s16x8*)((char*)As + swz128(row, seg * 2))     = *(const s16x8*)&ha[0];
    *(s16x8*)((char*)As + swz128(row, seg * 2 + 1)) = *(const s16x8*)&ha[8];
    // B: combine 4 KV-split partials for rows n0+row, head kk, d = seg*16..+16
    int bh = b * 4 + kk;
    int nr = n0 + row;
    float m0 = Mm[(0 * 16 + bh) * 2048 + nr], l0 = Ll[(0 * 16 + bh) * 2048 + nr];
    float m1 = Mm[(1 * 16 + bh) * 2048 + nr], l1 = Ll[(1 * 16 + bh) * 2048 + nr];
    float m2 = Mm[(2 * 16 + bh) * 2048 + nr], l2 = Ll[(2 * 16 + bh) * 2048 + nr];
    float m3 = Mm[(3 * 16 + bh) * 2048 + nr], l3 = Ll[(3 * 16 + bh) * 2048 + nr];
    float M = fmaxf(fmaxf(m0, m1), fmaxf(m2, m3));
    float w0 = l0 * exp2f(m0 - M), w1 = l1 * exp2f(m1 - M);
    float w2 = l2 * exp2f(m2 - M), w3 = l3 * exp2f(m3 - M);
    float inv = 1.f / (w0 + w1 + w2 + w3);
    w0 *= inv; w1 *= inv; w2 *= inv; w3 *= inv;
    float cb[16];
    {
      const short* p0 = &PO[((0 * 16 + bh) * 2048 + nr) * 64 + seg * 16];
      const short* p1 = &PO[((1 * 16 + bh) * 2048 + nr) * 64 + seg * 16];
      const short* p2 = &PO[((2 * 16 + bh) * 2048 + nr) * 64 + seg * 16];
      const short* p3 = &PO[((3 * 16 + bh) * 2048 + nr) * 64 + seg * 16];
      s16x8 a0 = *(const s16x8*)p0, a1 = *(const s16x8*)(p0 + 8);
      s16x8 b0 = *(const s16x8*)p1, b1 = *(const s16x8*)(p1 + 8);
      s16x8 c0 = *(const s16x8*)p2, c1 = *(const s16x8*)(p2 + 8);
      s16x8 d0 = *(const s16x8*)p3, d1 = *(const s16x8*)(p3 + 8);
#pragma unroll
      for (int j = 0; j < 8; ++j) {
        cb[j]     = w0 * h2f(a0[j]) + w1 * h2f(b0[j]) + w2 * h2f(c0[j]) + w3 * h2f(d0[j]);
        cb[j + 8] = w0 * h2f(a1[j]) + w1 * h2f(b1[j]) + w2 * h2f(c1[j]) + w3 * h2f(d1[j]);
      }
    }
    short hb[16];
#pragma unroll
    for (int j = 0; j < 16; ++j) hb[j] = f2h(cb[j]);
    *(s16x8*)((char*)Bs + swz128(row, seg * 2))     = *(const s16x8*)&hb[0];
    *(s16x8*)((char*)Bs + swz128(row, seg * 2 + 1)) = *(const s16x8*)&hb[8];
    __syncthreads();
#pragma unroll
    for (int ks = 0; ks < 2; ++ks) {
      f16x8 af[2], bfr[2];
#pragma unroll
      for (int f = 0; f < 2; ++f) {
        af[f]  = *(const f16x8*)((char*)As + swz128(wr * 32 + f * 16 + c, ks * 4 + g));
        bfr[f] = *(const f16x8*)((char*)Bs + swz128(wc * 32 + f * 16 + c, ks * 4 + g));
      }
#pragma unroll
      for (int i = 0; i < 2; ++i)
#pragma unroll
        for (int j = 0; j < 2; ++j)
          acc[i][j] = MFMA(af[i], bfr[j], acc[i][j]);
    }
  }
#pragma unroll
  for (int i = 0; i < 2; ++i) {
    int ob = o0 + wr * 32 + i * 16 + g * 4;
#pragma unroll
    for (int j = 0; j < 2; ++j) {
      int n = n0 + wc * 32 + j * 16 + c;
#pragma unroll
      for (int r = 0; r < 4; ++r)
        out[(b * 256 + ob + r) * 2048 + n] = acc[i][j][r] + bm[ob + r];
    }
  }
}

extern "C" void kernel_launch(void* const* d_in, const int* in_sizes, int n_in,
                              void* d_out, int out_size, void* d_ws, size_t ws_size,
                              hipStream_t stream) {
  (void)in_sizes; (void)n_in; (void)out_size; (void)ws_size;
  const float* q   = (const float*)d_in[0];
  const float* k   = (const float*)d_in[1];
  const float* v   = (const float*)d_in[2];
  const float* enc = (const float*)d_in[3];
  const float* Wq  = (const float*)d_in[4];
  const float* bq  = (const float*)d_in[5];
  const float* Wk  = (const float*)d_in[6];
  const float* bk  = (const float*)d_in[7];
  const float* Wv  = (const float*)d_in[8];
  const float* bv  = (const float*)d_in[9];
  const float* Wm  = (const float*)d_in[10];
  const float* bm  = (const float*)d_in[11];
  char* ws = (char*)d_ws;
  float* out = (float*)d_out;
  hipLaunchKernelGGL(k_trans, dim3(32, 4, 12), dim3(256), 0, stream, q, k, v, ws);
  hipLaunchKernelGGL(k_proj, dim3(32, 4, 12), dim3(256), 0, stream, Wq, Wk, Wv, enc, bq, bk, bv, ws);
  hipLaunchKernelGGL(k_attn, dim3(32, 16, 4), dim3(256), 0, stream, ws);
  hipLaunchKernelGGL(k_final, dim3(32, 4, 4), dim3(256), 0, stream, Wm, bm, out, ws);
}